// Round 3
// baseline (713.457 us; speedup 1.0000x reference)
//
#include <hip/hip_runtime.h>

#define NIMG 64
#define H 512
#define W 512

constexpr float THR_64  = 50.0f / 255.0f;          // level_idx=1: 64x64 details
constexpr float THR_128 = 50.0f / 2.0f / 255.0f;   // level_idx=2: 128x128
constexpr float THR_256 = 50.0f / 4.0f / 255.0f;   // level_idx=3: 256x256

__device__ __forceinline__ float wave_sum(float v) {
#pragma unroll
    for (int o = 32; o > 0; o >>= 1) v += __shfl_down(v, o, 64);
    return v;
}

__device__ __forceinline__ float clip01(float x) {
    return fminf(fmaxf(x, 0.0f), 1.0f);
}

__device__ __forceinline__ float4 clip4(float4 p) {
    p.x = clip01(p.x); p.y = clip01(p.y); p.z = clip01(p.z); p.w = clip01(p.w);
    return p;
}

// Kernel A: clip + n2v + tv + level-1 Haar. No LDS main path, no mid barrier.
// Wave = half row-pair: rows {2pr, 2pr+1}, cols [256h, 256h+256).
// Lane l owns cols 256h+4l .. +4  ->  every load is a dense 1KB wave access.
// Block = 4 waves. Grid = 64 imgs * 512 half-row-pairs / 4 = 8192 blocks.
__global__ __launch_bounds__(256) void kA(const float* __restrict__ pred,
                                          const float* __restrict__ noisy,
                                          const int* __restrict__ mask,
                                          float* __restrict__ acc,
                                          float* __restrict__ ll1) {
    __shared__ float red[4][4];

    const int tid = threadIdx.x;
    const int lane = tid & 63;
    const int wv = tid >> 6;
    const int bid = blockIdx.x;
    const int n = bid >> 7;                    // 128 blocks per image
    const int idx = ((bid & 127) << 2) + wv;   // 0..511
    const int pr = idx >> 1;                   // row pair 0..255
    const int h = idx & 1;                     // half 0..1
    const int r0 = pr << 1;
    const int col = (h << 8) + (lane << 2);
    const size_t base = (size_t)n * (H * W) + (size_t)r0 * W + col;

    // --- coalesced loads, all independent ---
    float4 p0 = *reinterpret_cast<const float4*>(pred + base);
    float4 p1 = *reinterpret_cast<const float4*>(pred + base + W);
    float4 nz0 = *reinterpret_cast<const float4*>(noisy + base);
    float4 nz1 = *reinterpret_cast<const float4*>(noisy + base + W);
    int4 mk0 = *reinterpret_cast<const int4*>(mask + base);
    int4 mk1 = *reinterpret_cast<const int4*>(mask + base + W);
    float4 hal = make_float4(0, 0, 0, 0);
    const bool has_halo = (pr > 0);            // wave-uniform
    if (has_halo) hal = clip4(*reinterpret_cast<const float4*>(pred + base - W));
    // seam between col 255 and 256: left-half wave, lane 63 loads col 256
    float e0 = 0.0f, e1 = 0.0f;
    const bool edge = (h == 0) && (lane == 63);
    if (edge) {
        e0 = clip01(pred[base + 4]);
        e1 = clip01(pred[base + W + 4]);
    }

    p0 = clip4(p0); p1 = clip4(p1);

    // --- n2v ---
    float n2v = 0.0f, msum = 0.0f;
    {
        float m;
        m = mk0.x ? 1.f : 0.f; n2v += fabsf(p0.x - nz0.x) * m; msum += m;
        m = mk0.y ? 1.f : 0.f; n2v += fabsf(p0.y - nz0.y) * m; msum += m;
        m = mk0.z ? 1.f : 0.f; n2v += fabsf(p0.z - nz0.z) * m; msum += m;
        m = mk0.w ? 1.f : 0.f; n2v += fabsf(p0.w - nz0.w) * m; msum += m;
        m = mk1.x ? 1.f : 0.f; n2v += fabsf(p1.x - nz1.x) * m; msum += m;
        m = mk1.y ? 1.f : 0.f; n2v += fabsf(p1.y - nz1.y) * m; msum += m;
        m = mk1.z ? 1.f : 0.f; n2v += fabsf(p1.z - nz1.z) * m; msum += m;
        m = mk1.w ? 1.f : 0.f; n2v += fabsf(p1.w - nz1.w) * m; msum += m;
    }

    // --- TV ---
    float tv = 0.0f;
    // horizontal interior diffs
    tv += fabsf(p0.y - p0.x) + fabsf(p0.z - p0.y) + fabsf(p0.w - p0.z);
    tv += fabsf(p1.y - p1.x) + fabsf(p1.z - p1.y) + fabsf(p1.w - p1.z);
    // horizontal boundary to next lane
    float nxt0 = __shfl_down(p0.x, 1, 64);
    float nxt1 = __shfl_down(p1.x, 1, 64);
    if (lane < 63) tv += fabsf(nxt0 - p0.w) + fabsf(nxt1 - p1.w);
    if (edge) tv += fabsf(e0 - p0.w) + fabsf(e1 - p1.w);
    // vertical r0 -> r1
    tv += fabsf(p1.x - p0.x) + fabsf(p1.y - p0.y)
        + fabsf(p1.z - p0.z) + fabsf(p1.w - p0.w);
    // vertical halo (r0-1) -> r0
    if (has_halo) {
        tv += fabsf(p0.x - hal.x) + fabsf(p0.y - hal.y)
            + fabsf(p0.z - hal.z) + fabsf(p0.w - hal.w);
    }

    // --- level-1 Haar: 2 quads per lane ---
    float wav = 0.0f;
    float ll0, ll1v;
    {
        float a, b, c, d, ch, cv, cd;
        a = p0.x; b = p0.y; c = p1.x; d = p1.y;
        ll0 = (a + b + c + d) * 0.5f;
        ch = (a + b - c - d) * 0.5f; cv = (a - b + c - d) * 0.5f; cd = (a - b - c + d) * 0.5f;
        wav += fminf(fabsf(ch), THR_256) + fminf(fabsf(cv), THR_256) + fminf(fabsf(cd), THR_256);
        a = p0.z; b = p0.w; c = p1.z; d = p1.w;
        ll1v = (a + b + c + d) * 0.5f;
        ch = (a + b - c - d) * 0.5f; cv = (a - b + c - d) * 0.5f; cd = (a - b - c + d) * 0.5f;
        wav += fminf(fabsf(ch), THR_256) + fminf(fabsf(cv), THR_256) + fminf(fabsf(cd), THR_256);
    }
    // LL1 row pr, cols [128h + 2l, +2)
    *reinterpret_cast<float2*>(ll1 + (size_t)n * 65536 + (size_t)pr * 256 + (h << 7) + (lane << 1)) =
        make_float2(ll0, ll1v);

    // --- block reduction ---
    float v0 = wave_sum(n2v);
    float v1 = wave_sum(msum);
    float v2 = wave_sum(tv);
    float v3 = wave_sum(wav);
    if (lane == 0) { red[wv][0] = v0; red[wv][1] = v1; red[wv][2] = v2; red[wv][3] = v3; }
    __syncthreads();
    if (tid == 0) {
        atomicAdd(acc + 0, red[0][0] + red[1][0] + red[2][0] + red[3][0]);
        atomicAdd(acc + 1, red[0][1] + red[1][1] + red[2][1] + red[3][1]);
        atomicAdd(acc + 2, red[0][2] + red[1][2] + red[2][2] + red[3][2]);
        atomicAdd(acc + 3, red[0][3] + red[1][3] + red[2][3] + red[3][3]);
    }
}

// Kernel BC: fused level-2 + level-3 + final compose (last-block ticket).
// Block = 32x32 LL1 tile -> 16x16 LL2 in LDS -> 8x8 level-3 quads.
// Grid = 64 imgs * 64 tiles = 4096 blocks.
__global__ __launch_bounds__(256) void kBC(const float* __restrict__ ll1,
                                           float* __restrict__ acc,
                                           float* __restrict__ out) {
    __shared__ float tile[16][17];
    __shared__ float red2[4];
    __shared__ float red3[1];

    const int tid = threadIdx.x;
    const int bid = blockIdx.x;
    const int n = bid >> 6;
    const int t = bid & 63;
    const int R = (t >> 3) << 5;       // tile row origin in LL1
    const int C = (t & 7) << 5;        // tile col origin
    const int qr = tid >> 4;           // 0..15
    const int qc = tid & 15;           // 0..15

    const float* src = ll1 + (size_t)n * 65536 + (size_t)(R + 2 * qr) * 256 + C + 2 * qc;
    float2 top = *reinterpret_cast<const float2*>(src);
    float2 bot = *reinterpret_cast<const float2*>(src + 256);
    float a = top.x, b = top.y, c = bot.x, d = bot.y;
    float ll2v = (a + b + c + d) * 0.5f;
    float ch = (a + b - c - d) * 0.5f;
    float cv = (a - b + c - d) * 0.5f;
    float cd = (a - b - c + d) * 0.5f;
    float wav2 = fminf(fabsf(ch), THR_128) + fminf(fabsf(cv), THR_128) + fminf(fabsf(cd), THR_128);
    tile[qr][qc] = ll2v;

    float v2 = wave_sum(wav2);
    const int lane = tid & 63, wv = tid >> 6;
    if (lane == 0) red2[wv] = v2;
    __syncthreads();

    // level 3: 64 quads, wave 0 only
    if (tid < 64) {
        int qr3 = tid >> 3, qc3 = tid & 7;
        a = tile[2 * qr3][2 * qc3];     b = tile[2 * qr3][2 * qc3 + 1];
        c = tile[2 * qr3 + 1][2 * qc3]; d = tile[2 * qr3 + 1][2 * qc3 + 1];
        ch = (a + b - c - d) * 0.5f;
        cv = (a - b + c - d) * 0.5f;
        cd = (a - b - c + d) * 0.5f;
        float wav3 = fminf(fabsf(ch), THR_64) + fminf(fabsf(cv), THR_64) + fminf(fabsf(cd), THR_64);
        wav3 = wave_sum(wav3);
        if (tid == 0) red3[0] = wav3;
    }
    __syncthreads();

    if (tid == 0) {
        atomicAdd(acc + 4, red2[0] + red2[1] + red2[2] + red2[3]);
        atomicAdd(acc + 5, red3[0]);
        __threadfence();
        unsigned ticket = atomicAdd(reinterpret_cast<unsigned*>(acc + 8), 1u);
        if (ticket == gridDim.x - 1) {
            // read at the coherent point (atomic RMW with 0)
            float a0 = atomicAdd(acc + 0, 0.0f);
            float a1 = atomicAdd(acc + 1, 0.0f);
            float a2 = atomicAdd(acc + 2, 0.0f);
            float a3 = atomicAdd(acc + 3, 0.0f);
            float a4 = atomicAdd(acc + 4, 0.0f);
            float a5 = atomicAdd(acc + 5, 0.0f);
            float n2v = a0 / fmaxf(a1, 1.0f);
            float tv = a2 / 16744448.0f;                   // 64*511*512 (both terms)
            float wav = a3 * (1.0f / 37748736.0f)          // (1/3) / (3*64*256*256)
                      + a4 * (1.0f / 6291456.0f)           // (1/2) / (3*64*128*128)
                      + a5 * (1.0f / 786432.0f);           // 1     / (3*64*64*64)
            out[0] = 1.0f * n2v + 0.2f * wav + 0.01f * tv;
        }
    }
}

extern "C" void kernel_launch(void* const* d_in, const int* in_sizes, int n_in,
                              void* d_out, int out_size, void* d_ws, size_t ws_size,
                              hipStream_t stream) {
    (void)in_sizes; (void)n_in; (void)out_size; (void)ws_size;
    const float* pred  = (const float*)d_in[0];
    const float* noisy = (const float*)d_in[1];
    const int*   mask  = (const int*)d_in[2];

    float* acc = (float*)d_ws;                   // [0..5] sums, [8] ticket counter
    float* ll1 = (float*)d_ws + 64;              // 64*256*256 floats = 16 MB

    hipMemsetAsync(d_ws, 0, 64 * sizeof(float), stream);
    kA<<<NIMG * 128, 256, 0, stream>>>(pred, noisy, mask, acc, ll1);
    kBC<<<NIMG * 64, 256, 0, stream>>>(ll1, acc, (float*)d_out);
}

// Round 4
// 202.144 us; speedup vs baseline: 3.5294x; 3.5294x over previous
//
#include <hip/hip_runtime.h>

#define NIMG 64
#define H 512
#define W 512

constexpr float THR_64  = 50.0f / 255.0f;          // level_idx=1: 64x64 details
constexpr float THR_128 = 50.0f / 2.0f / 255.0f;   // level_idx=2: 128x128
constexpr float THR_256 = 50.0f / 4.0f / 255.0f;   // level_idx=3: 256x256

__device__ __forceinline__ float wave_sum(float v) {
#pragma unroll
    for (int o = 32; o > 0; o >>= 1) v += __shfl_down(v, o, 64);
    return v;
}

__device__ __forceinline__ float clip01(float x) {
    return fminf(fmaxf(x, 0.0f), 1.0f);
}

__device__ __forceinline__ float4 clip4(float4 p) {
    p.x = clip01(p.x); p.y = clip01(p.y); p.z = clip01(p.z); p.w = clip01(p.w);
    return p;
}

// Kernel A: clip + n2v + tv + level-1 Haar. NO ATOMICS — per-block partials
// stored to pA[bid]. Block = 4 waves; each wave loops over 4 half-row-pairs
// (rows {2pr,2pr+1}, 256-col half, lane l owns cols 4l..4l+4 within the half).
// Grid = 64 imgs * 32 tiles = 2048 blocks; tile = 16 rows.
__global__ __launch_bounds__(256) void kA(const float* __restrict__ pred,
                                          const float* __restrict__ noisy,
                                          const int* __restrict__ mask,
                                          float4* __restrict__ pA,
                                          float* __restrict__ ll1) {
    __shared__ float red[4][4];

    const int tid = threadIdx.x;
    const int lane = tid & 63;
    const int wv = tid >> 6;
    const int bid = blockIdx.x;
    const int n = bid >> 5;                    // image
    const int tile = bid & 31;                 // 16-row tile

    float n2v = 0.0f, msum = 0.0f, tv = 0.0f, wav = 0.0f;

#pragma unroll
    for (int k = 0; k < 4; ++k) {
        const int idx = (k << 2) + wv;         // 0..15
        const int prl = idx >> 1;              // local row pair 0..7
        const int h = idx & 1;                 // half 0..1
        const int pr = (tile << 3) + prl;      // global row pair 0..255
        const int r0 = pr << 1;
        const int col = (h << 8) + (lane << 2);
        const size_t base = (size_t)n * (H * W) + (size_t)r0 * W + col;

        // --- coalesced independent loads (dense 1KB per wave per load) ---
        float4 p0 = *reinterpret_cast<const float4*>(pred + base);
        float4 p1 = *reinterpret_cast<const float4*>(pred + base + W);
        float4 nz0 = *reinterpret_cast<const float4*>(noisy + base);
        float4 nz1 = *reinterpret_cast<const float4*>(noisy + base + W);
        int4 mk0 = *reinterpret_cast<const int4*>(mask + base);
        int4 mk1 = *reinterpret_cast<const int4*>(mask + base + W);
        float4 hal = make_float4(0, 0, 0, 0);
        const bool has_halo = (pr > 0);        // wave-uniform
        if (has_halo) hal = clip4(*reinterpret_cast<const float4*>(pred + base - W));
        // seam col 255|256: left-half wave, lane 63
        float e0 = 0.0f, e1 = 0.0f;
        const bool edge = (h == 0) && (lane == 63);
        if (edge) {
            e0 = clip01(pred[base + 4]);
            e1 = clip01(pred[base + W + 4]);
        }

        p0 = clip4(p0); p1 = clip4(p1);

        // --- n2v ---
        {
            float m;
            m = mk0.x ? 1.f : 0.f; n2v += fabsf(p0.x - nz0.x) * m; msum += m;
            m = mk0.y ? 1.f : 0.f; n2v += fabsf(p0.y - nz0.y) * m; msum += m;
            m = mk0.z ? 1.f : 0.f; n2v += fabsf(p0.z - nz0.z) * m; msum += m;
            m = mk0.w ? 1.f : 0.f; n2v += fabsf(p0.w - nz0.w) * m; msum += m;
            m = mk1.x ? 1.f : 0.f; n2v += fabsf(p1.x - nz1.x) * m; msum += m;
            m = mk1.y ? 1.f : 0.f; n2v += fabsf(p1.y - nz1.y) * m; msum += m;
            m = mk1.z ? 1.f : 0.f; n2v += fabsf(p1.z - nz1.z) * m; msum += m;
            m = mk1.w ? 1.f : 0.f; n2v += fabsf(p1.w - nz1.w) * m; msum += m;
        }

        // --- TV ---
        tv += fabsf(p0.y - p0.x) + fabsf(p0.z - p0.y) + fabsf(p0.w - p0.z);
        tv += fabsf(p1.y - p1.x) + fabsf(p1.z - p1.y) + fabsf(p1.w - p1.z);
        float nxt0 = __shfl_down(p0.x, 1, 64);
        float nxt1 = __shfl_down(p1.x, 1, 64);
        if (lane < 63) tv += fabsf(nxt0 - p0.w) + fabsf(nxt1 - p1.w);
        if (edge) tv += fabsf(e0 - p0.w) + fabsf(e1 - p1.w);
        tv += fabsf(p1.x - p0.x) + fabsf(p1.y - p0.y)
            + fabsf(p1.z - p0.z) + fabsf(p1.w - p0.w);
        if (has_halo) {
            tv += fabsf(p0.x - hal.x) + fabsf(p0.y - hal.y)
                + fabsf(p0.z - hal.z) + fabsf(p0.w - hal.w);
        }

        // --- level-1 Haar: 2 quads per lane ---
        float a, b, c, d, ch, cv, cd, ll0, ll1v;
        a = p0.x; b = p0.y; c = p1.x; d = p1.y;
        ll0 = (a + b + c + d) * 0.5f;
        ch = (a + b - c - d) * 0.5f; cv = (a - b + c - d) * 0.5f; cd = (a - b - c + d) * 0.5f;
        wav += fminf(fabsf(ch), THR_256) + fminf(fabsf(cv), THR_256) + fminf(fabsf(cd), THR_256);
        a = p0.z; b = p0.w; c = p1.z; d = p1.w;
        ll1v = (a + b + c + d) * 0.5f;
        ch = (a + b - c - d) * 0.5f; cv = (a - b + c - d) * 0.5f; cd = (a - b - c + d) * 0.5f;
        wav += fminf(fabsf(ch), THR_256) + fminf(fabsf(cv), THR_256) + fminf(fabsf(cd), THR_256);

        *reinterpret_cast<float2*>(ll1 + (size_t)n * 65536 + (size_t)pr * 256 +
                                   (h << 7) + (lane << 1)) = make_float2(ll0, ll1v);
    }

    // --- block reduction -> single plain store (no atomics) ---
    float v0 = wave_sum(n2v);
    float v1 = wave_sum(msum);
    float v2 = wave_sum(tv);
    float v3 = wave_sum(wav);
    if (lane == 0) { red[wv][0] = v0; red[wv][1] = v1; red[wv][2] = v2; red[wv][3] = v3; }
    __syncthreads();
    if (tid == 0) {
        pA[bid] = make_float4(red[0][0] + red[1][0] + red[2][0] + red[3][0],
                              red[0][1] + red[1][1] + red[2][1] + red[3][1],
                              red[0][2] + red[1][2] + red[2][2] + red[3][2],
                              red[0][3] + red[1][3] + red[2][3] + red[3][3]);
    }
}

// Kernel BC: fused level-2 + level-3. Haar quads are non-overlapping, so an
// image splits into 4 horizontal slabs of 64 LL1 rows. Block = one slab:
// level-2 quads 32x128 (16/thread) -> LL2 slab in LDS -> level-3 quads 16x64
// (4/thread). Per-block partials to pBC[bid]. Grid = 64*4 = 256 blocks.
__global__ __launch_bounds__(256) void kBC(const float* __restrict__ ll1,
                                           float2* __restrict__ pBC) {
    __shared__ float ll2[32][129];
    __shared__ float red2[4], red3[4];

    const int tid = threadIdx.x;
    const int lane = tid & 63, wv = tid >> 6;
    const int bid = blockIdx.x;
    const int n = bid >> 2;
    const int s = bid & 3;                       // slab: LL1 rows [64s, 64s+64)
    const float* src = ll1 + (size_t)n * 65536 + (size_t)(s << 6) * 256;

    float wav2 = 0.0f;
#pragma unroll
    for (int i = 0; i < 16; ++i) {
        int q = (i << 8) + tid;                  // 0..4095
        int qr = q >> 7;                         // 0..31
        int qc = q & 127;                        // 0..127
        float2 top = *reinterpret_cast<const float2*>(src + (2 * qr) * 256 + 2 * qc);
        float2 bot = *reinterpret_cast<const float2*>(src + (2 * qr + 1) * 256 + 2 * qc);
        float a = top.x, b = top.y, c = bot.x, d = bot.y;
        float ch = (a + b - c - d) * 0.5f;
        float cv = (a - b + c - d) * 0.5f;
        float cd = (a - b - c + d) * 0.5f;
        wav2 += fminf(fabsf(ch), THR_128) + fminf(fabsf(cv), THR_128) + fminf(fabsf(cd), THR_128);
        ll2[qr][qc] = (a + b + c + d) * 0.5f;
    }
    __syncthreads();

    float wav3 = 0.0f;
#pragma unroll
    for (int i = 0; i < 4; ++i) {
        int q = (i << 8) + tid;                  // 0..1023
        int qr = q >> 6;                         // 0..15
        int qc = q & 63;                         // 0..63
        float a = ll2[2 * qr][2 * qc],     b = ll2[2 * qr][2 * qc + 1];
        float c = ll2[2 * qr + 1][2 * qc], d = ll2[2 * qr + 1][2 * qc + 1];
        float ch = (a + b - c - d) * 0.5f;
        float cv = (a - b + c - d) * 0.5f;
        float cd = (a - b - c + d) * 0.5f;
        wav3 += fminf(fabsf(ch), THR_64) + fminf(fabsf(cv), THR_64) + fminf(fabsf(cd), THR_64);
    }

    float v2 = wave_sum(wav2);
    float v3 = wave_sum(wav3);
    if (lane == 0) { red2[wv] = v2; red3[wv] = v3; }
    __syncthreads();
    if (tid == 0) {
        pBC[bid] = make_float2(red2[0] + red2[1] + red2[2] + red2[3],
                               red3[0] + red3[1] + red3[2] + red3[3]);
    }
}

// Kernel D: reduce partials (2048 float4 + 256 float2), compose scalar.
__global__ __launch_bounds__(256) void kD(const float4* __restrict__ pA,
                                          const float2* __restrict__ pBC,
                                          float* __restrict__ out) {
    __shared__ float red[4][6];
    const int tid = threadIdx.x;
    const int lane = tid & 63, wv = tid >> 6;

    float s0 = 0, s1 = 0, s2 = 0, s3 = 0, s4 = 0, s5 = 0;
#pragma unroll
    for (int j = 0; j < 8; ++j) {
        float4 v = pA[tid + (j << 8)];
        s0 += v.x; s1 += v.y; s2 += v.z; s3 += v.w;
    }
    {
        float2 w = pBC[tid];                     // exactly 256 entries
        s4 += w.x; s5 += w.y;
    }
    s0 = wave_sum(s0); s1 = wave_sum(s1); s2 = wave_sum(s2);
    s3 = wave_sum(s3); s4 = wave_sum(s4); s5 = wave_sum(s5);
    if (lane == 0) {
        red[wv][0] = s0; red[wv][1] = s1; red[wv][2] = s2;
        red[wv][3] = s3; red[wv][4] = s4; red[wv][5] = s5;
    }
    __syncthreads();
    if (tid == 0) {
        float a0 = red[0][0] + red[1][0] + red[2][0] + red[3][0];
        float a1 = red[0][1] + red[1][1] + red[2][1] + red[3][1];
        float a2 = red[0][2] + red[1][2] + red[2][2] + red[3][2];
        float a3 = red[0][3] + red[1][3] + red[2][3] + red[3][3];
        float a4 = red[0][4] + red[1][4] + red[2][4] + red[3][4];
        float a5 = red[0][5] + red[1][5] + red[2][5] + red[3][5];
        float n2v = a0 / fmaxf(a1, 1.0f);
        float tv = a2 / 16744448.0f;                   // 64*511*512 (both terms)
        float wav = a3 * (1.0f / 37748736.0f)          // (1/3) / (3*64*256*256)
                  + a4 * (1.0f / 6291456.0f)           // (1/2) / (3*64*128*128)
                  + a5 * (1.0f / 786432.0f);           // 1     / (3*64*64*64)
        out[0] = 1.0f * n2v + 0.2f * wav + 0.01f * tv;
    }
}

extern "C" void kernel_launch(void* const* d_in, const int* in_sizes, int n_in,
                              void* d_out, int out_size, void* d_ws, size_t ws_size,
                              hipStream_t stream) {
    (void)in_sizes; (void)n_in; (void)out_size; (void)ws_size;
    const float* pred  = (const float*)d_in[0];
    const float* noisy = (const float*)d_in[1];
    const int*   mask  = (const int*)d_in[2];

    float4* pA  = (float4*)d_ws;                          // 2048 * 16 B = 32 KB
    float2* pBC = (float2*)((char*)d_ws + 2048 * 16);     // 256 * 8 B
    float*  ll1 = (float*)((char*)d_ws + 65536);          // 64*256*256 floats = 16 MB

    kA<<<NIMG * 32, 256, 0, stream>>>(pred, noisy, mask, pA, ll1);
    kBC<<<NIMG * 4, 256, 0, stream>>>(ll1, pBC);
    kD<<<1, 256, 0, stream>>>(pA, pBC, (float*)d_out);
}

// Round 5
// 197.510 us; speedup vs baseline: 3.6123x; 1.0235x over previous
//
#include <hip/hip_runtime.h>

#define NIMG 64
#define H 512
#define W 512

constexpr float THR_64  = 50.0f / 255.0f;          // level_idx=1: 64x64 details
constexpr float THR_128 = 50.0f / 2.0f / 255.0f;   // level_idx=2: 128x128
constexpr float THR_256 = 50.0f / 4.0f / 255.0f;   // level_idx=3: 256x256

__device__ __forceinline__ float wave_sum(float v) {
#pragma unroll
    for (int o = 32; o > 0; o >>= 1) v += __shfl_down(v, o, 64);
    return v;
}

__device__ __forceinline__ float clip01(float x) {
    return fminf(fmaxf(x, 0.0f), 1.0f);
}

__device__ __forceinline__ float4 clip4(float4 p) {
    p.x = clip01(p.x); p.y = clip01(p.y); p.z = clip01(p.z); p.w = clip01(p.w);
    return p;
}

// Kernel A: clip + n2v + tv + level-1 AND level-2 Haar, fully in-register.
// Wave = 4 consecutive rows (r0..r0+3, r0=4q) x 256-col half; lane l owns
// cols [256h+4l, +4). The lane's four level-1 LL values form exactly one
// level-2 quad (rows 2q,2q+1 x cols 2l,2l+1 of LL1) -> level 2 is lane-local.
// Writes only LL2 (4 MB). 13 independent vector loads up front; no atomics.
// Grid = 16384 waves / 4 = 4096 blocks.
__global__ __launch_bounds__(256, 4) void kA(const float* __restrict__ pred,
                                             const float* __restrict__ noisy,
                                             const int* __restrict__ mask,
                                             float4* __restrict__ pA,
                                             float* __restrict__ pW2,
                                             float* __restrict__ ll2) {
    __shared__ float red[4][5];

    const int tid = threadIdx.x;
    const int lane = tid & 63;
    const int wv = tid >> 6;
    const int w = (blockIdx.x << 2) + wv;      // 0..16383
    const int n = w >> 8;                      // image
    const int rem = w & 255;
    const int q = rem >> 1;                    // row quad 0..127 (rows 4q..4q+3)
    const int h = rem & 1;                     // 256-col half
    const int r0 = q << 2;
    const int col = (h << 8) + (lane << 2);
    const size_t base = (size_t)n * (H * W) + (size_t)r0 * W + col;
    const bool has_halo = (q > 0);             // wave-uniform
    const size_t baseH = has_halo ? (base - W) : base;  // clamped (term zeroed)

    // --- 13 independent coalesced loads, all issued up front ---
    float4 p0 = *reinterpret_cast<const float4*>(pred + base);
    float4 p1 = *reinterpret_cast<const float4*>(pred + base + W);
    float4 p2 = *reinterpret_cast<const float4*>(pred + base + 2 * W);
    float4 p3 = *reinterpret_cast<const float4*>(pred + base + 3 * W);
    float4 hl = *reinterpret_cast<const float4*>(pred + baseH);
    float4 nz0 = *reinterpret_cast<const float4*>(noisy + base);
    float4 nz1 = *reinterpret_cast<const float4*>(noisy + base + W);
    float4 nz2 = *reinterpret_cast<const float4*>(noisy + base + 2 * W);
    float4 nz3 = *reinterpret_cast<const float4*>(noisy + base + 3 * W);
    int4 mk0 = *reinterpret_cast<const int4*>(mask + base);
    int4 mk1 = *reinterpret_cast<const int4*>(mask + base + W);
    int4 mk2 = *reinterpret_cast<const int4*>(mask + base + 2 * W);
    int4 mk3 = *reinterpret_cast<const int4*>(mask + base + 3 * W);
    // seam col 255|256: only left-half lane 63 (4 scalar loads, 1 active lane)
    float e0 = 0.f, e1 = 0.f, e2 = 0.f, e3 = 0.f;
    const bool edge = (h == 0) && (lane == 63);
    if (edge) {
        e0 = clip01(pred[base + 4]);
        e1 = clip01(pred[base + W + 4]);
        e2 = clip01(pred[base + 2 * W + 4]);
        e3 = clip01(pred[base + 3 * W + 4]);
    }

    p0 = clip4(p0); p1 = clip4(p1); p2 = clip4(p2); p3 = clip4(p3);
    hl = clip4(hl);

    // --- n2v ---
    float n2v = 0.0f, msum = 0.0f;
    {
        float m;
        m = mk0.x ? 1.f : 0.f; n2v += fabsf(p0.x - nz0.x) * m; msum += m;
        m = mk0.y ? 1.f : 0.f; n2v += fabsf(p0.y - nz0.y) * m; msum += m;
        m = mk0.z ? 1.f : 0.f; n2v += fabsf(p0.z - nz0.z) * m; msum += m;
        m = mk0.w ? 1.f : 0.f; n2v += fabsf(p0.w - nz0.w) * m; msum += m;
        m = mk1.x ? 1.f : 0.f; n2v += fabsf(p1.x - nz1.x) * m; msum += m;
        m = mk1.y ? 1.f : 0.f; n2v += fabsf(p1.y - nz1.y) * m; msum += m;
        m = mk1.z ? 1.f : 0.f; n2v += fabsf(p1.z - nz1.z) * m; msum += m;
        m = mk1.w ? 1.f : 0.f; n2v += fabsf(p1.w - nz1.w) * m; msum += m;
        m = mk2.x ? 1.f : 0.f; n2v += fabsf(p2.x - nz2.x) * m; msum += m;
        m = mk2.y ? 1.f : 0.f; n2v += fabsf(p2.y - nz2.y) * m; msum += m;
        m = mk2.z ? 1.f : 0.f; n2v += fabsf(p2.z - nz2.z) * m; msum += m;
        m = mk2.w ? 1.f : 0.f; n2v += fabsf(p2.w - nz2.w) * m; msum += m;
        m = mk3.x ? 1.f : 0.f; n2v += fabsf(p3.x - nz3.x) * m; msum += m;
        m = mk3.y ? 1.f : 0.f; n2v += fabsf(p3.y - nz3.y) * m; msum += m;
        m = mk3.z ? 1.f : 0.f; n2v += fabsf(p3.z - nz3.z) * m; msum += m;
        m = mk3.w ? 1.f : 0.f; n2v += fabsf(p3.w - nz3.w) * m; msum += m;
    }

    // --- TV ---
    float tv = 0.0f;
    // horizontal interior
    tv += fabsf(p0.y - p0.x) + fabsf(p0.z - p0.y) + fabsf(p0.w - p0.z);
    tv += fabsf(p1.y - p1.x) + fabsf(p1.z - p1.y) + fabsf(p1.w - p1.z);
    tv += fabsf(p2.y - p2.x) + fabsf(p2.z - p2.y) + fabsf(p2.w - p2.z);
    tv += fabsf(p3.y - p3.x) + fabsf(p3.z - p3.y) + fabsf(p3.w - p3.z);
    // horizontal lane boundary
    float nx0 = __shfl_down(p0.x, 1, 64);
    float nx1 = __shfl_down(p1.x, 1, 64);
    float nx2 = __shfl_down(p2.x, 1, 64);
    float nx3 = __shfl_down(p3.x, 1, 64);
    if (lane < 63) {
        tv += fabsf(nx0 - p0.w) + fabsf(nx1 - p1.w)
            + fabsf(nx2 - p2.w) + fabsf(nx3 - p3.w);
    }
    if (edge) {
        tv += fabsf(e0 - p0.w) + fabsf(e1 - p1.w)
            + fabsf(e2 - p2.w) + fabsf(e3 - p3.w);
    }
    // vertical internal (3 diffs) + halo
    tv += fabsf(p1.x - p0.x) + fabsf(p1.y - p0.y) + fabsf(p1.z - p0.z) + fabsf(p1.w - p0.w);
    tv += fabsf(p2.x - p1.x) + fabsf(p2.y - p1.y) + fabsf(p2.z - p1.z) + fabsf(p2.w - p1.w);
    tv += fabsf(p3.x - p2.x) + fabsf(p3.y - p2.y) + fabsf(p3.z - p2.z) + fabsf(p3.w - p2.w);
    if (has_halo) {
        tv += fabsf(p0.x - hl.x) + fabsf(p0.y - hl.y)
            + fabsf(p0.z - hl.z) + fabsf(p0.w - hl.w);
    }

    // --- level-1 Haar: 4 quads per lane ---
    float wav1 = 0.0f;
    float llA0, llA1, llB0, llB1;
    {
        float a, b, c, d, ch, cv, cd;
        a = p0.x; b = p0.y; c = p1.x; d = p1.y;              // LL1 row 2q, col 2l
        llA0 = (a + b + c + d) * 0.5f;
        ch = (a + b - c - d) * 0.5f; cv = (a - b + c - d) * 0.5f; cd = (a - b - c + d) * 0.5f;
        wav1 += fminf(fabsf(ch), THR_256) + fminf(fabsf(cv), THR_256) + fminf(fabsf(cd), THR_256);
        a = p0.z; b = p0.w; c = p1.z; d = p1.w;              // LL1 row 2q, col 2l+1
        llA1 = (a + b + c + d) * 0.5f;
        ch = (a + b - c - d) * 0.5f; cv = (a - b + c - d) * 0.5f; cd = (a - b - c + d) * 0.5f;
        wav1 += fminf(fabsf(ch), THR_256) + fminf(fabsf(cv), THR_256) + fminf(fabsf(cd), THR_256);
        a = p2.x; b = p2.y; c = p3.x; d = p3.y;              // LL1 row 2q+1, col 2l
        llB0 = (a + b + c + d) * 0.5f;
        ch = (a + b - c - d) * 0.5f; cv = (a - b + c - d) * 0.5f; cd = (a - b - c + d) * 0.5f;
        wav1 += fminf(fabsf(ch), THR_256) + fminf(fabsf(cv), THR_256) + fminf(fabsf(cd), THR_256);
        a = p2.z; b = p2.w; c = p3.z; d = p3.w;              // LL1 row 2q+1, col 2l+1
        llB1 = (a + b + c + d) * 0.5f;
        ch = (a + b - c - d) * 0.5f; cv = (a - b + c - d) * 0.5f; cd = (a - b - c + d) * 0.5f;
        wav1 += fminf(fabsf(ch), THR_256) + fminf(fabsf(cv), THR_256) + fminf(fabsf(cd), THR_256);
    }

    // --- level-2 Haar: lane-local quad (llA0, llA1; llB0, llB1) ---
    float wav2;
    {
        float a = llA0, b = llA1, c = llB0, d = llB1;
        float ll2v = (a + b + c + d) * 0.5f;
        float ch = (a + b - c - d) * 0.5f;
        float cv = (a - b + c - d) * 0.5f;
        float cd = (a - b - c + d) * 0.5f;
        wav2 = fminf(fabsf(ch), THR_128) + fminf(fabsf(cv), THR_128) + fminf(fabsf(cd), THR_128);
        // LL2[n][q][64h + lane] — 256 B contiguous per wave
        ll2[(size_t)n * 16384 + (size_t)q * 128 + (h << 6) + lane] = ll2v;
    }

    // --- block reduction -> plain stores ---
    float v0 = wave_sum(n2v);
    float v1 = wave_sum(msum);
    float v2 = wave_sum(tv);
    float v3 = wave_sum(wav1);
    float v4 = wave_sum(wav2);
    if (lane == 0) {
        red[wv][0] = v0; red[wv][1] = v1; red[wv][2] = v2;
        red[wv][3] = v3; red[wv][4] = v4;
    }
    __syncthreads();
    if (tid == 0) {
        pA[blockIdx.x] = make_float4(red[0][0] + red[1][0] + red[2][0] + red[3][0],
                                     red[0][1] + red[1][1] + red[2][1] + red[3][1],
                                     red[0][2] + red[1][2] + red[2][2] + red[3][2],
                                     red[0][3] + red[1][3] + red[2][3] + red[3][3]);
        pW2[blockIdx.x] = red[0][4] + red[1][4] + red[2][4] + red[3][4];
    }
}

// Kernel C: level-3 details from LL2 (64x128x128, 4 MB). Grid = 128 blocks
// (half image each), 8 quads/thread. Partials to pC[bid].
__global__ __launch_bounds__(256) void kC(const float* __restrict__ ll2,
                                          float* __restrict__ pC) {
    __shared__ float red[4];
    const int tid = threadIdx.x;
    const int lane = tid & 63, wv = tid >> 6;
    const int bid = blockIdx.x;
    const int n = bid >> 1;
    const int s = bid & 1;                      // quad-row half [32s, 32s+32)
    const float* src = ll2 + (size_t)n * 16384;

    float wav3 = 0.0f;
#pragma unroll
    for (int i = 0; i < 8; ++i) {
        int u = (i << 8) + tid;                 // 0..2047
        int qr = (s << 5) + (u >> 6);           // 0..63
        int qc = u & 63;
        float2 top = *reinterpret_cast<const float2*>(src + (2 * qr) * 128 + 2 * qc);
        float2 bot = *reinterpret_cast<const float2*>(src + (2 * qr + 1) * 128 + 2 * qc);
        float a = top.x, b = top.y, c = bot.x, d = bot.y;
        float ch = (a + b - c - d) * 0.5f;
        float cv = (a - b + c - d) * 0.5f;
        float cd = (a - b - c + d) * 0.5f;
        wav3 += fminf(fabsf(ch), THR_64) + fminf(fabsf(cv), THR_64) + fminf(fabsf(cd), THR_64);
    }
    float v = wave_sum(wav3);
    if (lane == 0) red[wv] = v;
    __syncthreads();
    if (tid == 0) pC[bid] = red[0] + red[1] + red[2] + red[3];
}

// Kernel D: reduce partials (4096 float4 + 4096 float + 128 float), compose.
__global__ __launch_bounds__(256) void kD(const float4* __restrict__ pA,
                                          const float* __restrict__ pW2,
                                          const float* __restrict__ pC,
                                          float* __restrict__ out) {
    __shared__ float red[4][6];
    const int tid = threadIdx.x;
    const int lane = tid & 63, wv = tid >> 6;

    float s0 = 0, s1 = 0, s2 = 0, s3 = 0, s4 = 0, s5 = 0;
#pragma unroll
    for (int j = 0; j < 16; ++j) {
        float4 v = pA[tid + (j << 8)];
        s0 += v.x; s1 += v.y; s2 += v.z; s3 += v.w;
        s4 += pW2[tid + (j << 8)];
    }
    if (tid < 128) s5 = pC[tid];

    s0 = wave_sum(s0); s1 = wave_sum(s1); s2 = wave_sum(s2);
    s3 = wave_sum(s3); s4 = wave_sum(s4); s5 = wave_sum(s5);
    if (lane == 0) {
        red[wv][0] = s0; red[wv][1] = s1; red[wv][2] = s2;
        red[wv][3] = s3; red[wv][4] = s4; red[wv][5] = s5;
    }
    __syncthreads();
    if (tid == 0) {
        float a0 = red[0][0] + red[1][0] + red[2][0] + red[3][0];
        float a1 = red[0][1] + red[1][1] + red[2][1] + red[3][1];
        float a2 = red[0][2] + red[1][2] + red[2][2] + red[3][2];
        float a3 = red[0][3] + red[1][3] + red[2][3] + red[3][3];
        float a4 = red[0][4] + red[1][4] + red[2][4] + red[3][4];
        float a5 = red[0][5] + red[1][5] + red[2][5] + red[3][5];
        float n2v = a0 / fmaxf(a1, 1.0f);
        float tv = a2 / 16744448.0f;                   // 64*511*512 (both terms)
        float wav = a3 * (1.0f / 37748736.0f)          // (1/3) / (3*64*256*256)
                  + a4 * (1.0f / 6291456.0f)           // (1/2) / (3*64*128*128)
                  + a5 * (1.0f / 786432.0f);           // 1     / (3*64*64*64)
        out[0] = 1.0f * n2v + 0.2f * wav + 0.01f * tv;
    }
}

extern "C" void kernel_launch(void* const* d_in, const int* in_sizes, int n_in,
                              void* d_out, int out_size, void* d_ws, size_t ws_size,
                              hipStream_t stream) {
    (void)in_sizes; (void)n_in; (void)out_size; (void)ws_size;
    const float* pred  = (const float*)d_in[0];
    const float* noisy = (const float*)d_in[1];
    const int*   mask  = (const int*)d_in[2];

    float4* pA  = (float4*)d_ws;                          // 4096 * 16 B = 64 KB
    float*  pW2 = (float*)((char*)d_ws + 65536);          // 4096 * 4 B
    float*  pC  = (float*)((char*)d_ws + 81920);          // 128 * 4 B
    float*  ll2 = (float*)((char*)d_ws + 98304);          // 64*128*128 floats = 4 MB

    kA<<<4096, 256, 0, stream>>>(pred, noisy, mask, pA, pW2, ll2);
    kC<<<128, 256, 0, stream>>>(ll2, pC);
    kD<<<1, 256, 0, stream>>>(pA, pW2, pC, (float*)d_out);
}